// Round 4
// baseline (578.173 us; speedup 1.0000x reference)
//
#include <hip/hip_runtime.h>
#include <hip/hip_bf16.h>
#include <stdint.h>

#define N_NODES 8192
#define DIM 256

typedef __attribute__((ext_vector_type(8))) __bf16 bf16x8;
typedef __attribute__((ext_vector_type(4))) float f32x4;

__device__ __forceinline__ unsigned short f2bf(float f) {
  unsigned u = __builtin_bit_cast(unsigned, f);
  u += 0x7fffu + ((u >> 16) & 1u);
  return (unsigned short)(u >> 16);
}
__device__ __forceinline__ float bf2f(unsigned short h) {
  return __builtin_bit_cast(float, (unsigned)h << 16);
}
__device__ __forceinline__ unsigned pack2(float a, float b) {
  return (unsigned)f2bf(a) | ((unsigned)f2bf(b) << 16);
}
__device__ __forceinline__ void async16(const void* g, void* l) {
  __builtin_amdgcn_global_load_lds(
      (const __attribute__((address_space(1))) unsigned int*)g,
      (__attribute__((address_space(3))) unsigned int*)l, 16, 0, 0);
}

// ---------------------------------------------------------------------------
// Kernel 1 (fused, block-specialized):
//   blocks [0,256):      support u = x @ W^T (UNscaled, bf16) -> uT + urm
//                        2 output cols per thread; waves 2-3 retire after
//                        staging (halves total ds_read_b128 count).
//   blocks [256, 8448):  rowsum  dinv[i] = rsqrt(sum_j adj[i,j] + 1)
// ---------------------------------------------------------------------------
__global__ __launch_bounds__(256) void fused_pre_kernel(
    const float* __restrict__ adj, const float* __restrict__ x,
    const float* __restrict__ W, float* __restrict__ dinv,
    unsigned short* __restrict__ uT, unsigned short* __restrict__ urm) {
  __shared__ float4 xs[32 * 64];  // 32 KB
  __shared__ float red[4];
  int tid = threadIdx.x;

  if (blockIdx.x >= 256) {
    // ---- rowsum branch ----
    int row = blockIdx.x - 256;
    const float4* r = (const float4*)(adj + (size_t)row * N_NODES);
    float s = 0.f;
#pragma unroll
    for (int it = 0; it < 8; ++it) {
      float4 v = r[tid + it * 256];
      s += (v.x + v.y) + (v.z + v.w);
    }
#pragma unroll
    for (int off = 32; off > 0; off >>= 1) s += __shfl_down(s, off);
    if ((tid & 63) == 0) red[tid >> 6] = s;
    __syncthreads();
    if (tid == 0) {
      float tot = red[0] + red[1] + red[2] + red[3] + 1.0f;
      dinv[row] = rsqrtf(tot);
    }
    return;
  }

  // ---- support branch: u[j,n] = sum_c x[j,c] * W[n,c] ----
  int j0 = blockIdx.x * 32;
  const float4* xg = (const float4*)(x + (size_t)j0 * DIM);
#pragma unroll
  for (int it = 0; it < 8; ++it) xs[tid + it * 256] = xg[tid + it * 256];
  __syncthreads();
  if (tid >= 128) return;  // no barriers after this point

  int n0 = tid, n1 = tid + 128;
  float acc0[32], acc1[32];
#pragma unroll
  for (int j = 0; j < 32; ++j) { acc0[j] = 0.f; acc1[j] = 0.f; }
  const float4* w0 = (const float4*)(W + (size_t)n0 * DIM);
  const float4* w1 = (const float4*)(W + (size_t)n1 * DIM);
#pragma unroll 1
  for (int cc = 0; cc < 4; ++cc) {
    float4 wa[16], wb[16];
#pragma unroll
    for (int m = 0; m < 16; ++m) { wa[m] = w0[cc * 16 + m]; wb[m] = w1[cc * 16 + m]; }
#pragma unroll
    for (int j = 0; j < 32; ++j) {
      float s0 = 0.f, s1 = 0.f;
#pragma unroll
      for (int m = 0; m < 16; ++m) {
        float4 xv = xs[j * 64 + cc * 16 + m];  // LDS broadcast
        s0 += xv.x * wa[m].x + xv.y * wa[m].y + xv.z * wa[m].z + xv.w * wa[m].w;
        s1 += xv.x * wb[m].x + xv.y * wb[m].y + xv.z * wb[m].z + xv.w * wb[m].w;
      }
      acc0[j] += s0;
      acc1[j] += s1;
    }
  }
  // uT: 64 B contiguous per (thread, n); urm: coalesced across threads
#pragma unroll
  for (int g = 0; g < 4; ++g) {
    uint4 v0, v1;
    v0.x = pack2(acc0[g * 8 + 0], acc0[g * 8 + 1]);
    v0.y = pack2(acc0[g * 8 + 2], acc0[g * 8 + 3]);
    v0.z = pack2(acc0[g * 8 + 4], acc0[g * 8 + 5]);
    v0.w = pack2(acc0[g * 8 + 6], acc0[g * 8 + 7]);
    v1.x = pack2(acc1[g * 8 + 0], acc1[g * 8 + 1]);
    v1.y = pack2(acc1[g * 8 + 2], acc1[g * 8 + 3]);
    v1.z = pack2(acc1[g * 8 + 4], acc1[g * 8 + 5]);
    v1.w = pack2(acc1[g * 8 + 6], acc1[g * 8 + 7]);
    *(uint4*)(uT + (size_t)n0 * N_NODES + j0 + g * 8) = v0;
    *(uint4*)(uT + (size_t)n1 * N_NODES + j0 + g * 8) = v1;
  }
#pragma unroll
  for (int j = 0; j < 32; ++j) {
    urm[(size_t)(j0 + j) * DIM + n0] = f2bf(acc0[j]);
    urm[(size_t)(j0 + j) * DIM + n1] = f2bf(acc1[j]);
  }
}

// ---------------------------------------------------------------------------
// Kernel 2: split-K GEMM  part[s][i,k] = sum_{j} bf16(adj[i,j]*d_j)*u[j,k]
// Tile 64(M) x 256(N) x BK=32, 4 waves. A staged manually (fp32->bf16 + d_j
// scale); B staged ASYNC via global_load_lds width=16 into an unpadded
// 64 B/row layout with XOR column swizzle c = kq ^ ((n>>1)&3) (2-way bank
// aliasing on fragment reads = free). Double-buffered, one barrier/iter;
// DMAs + A loads for iter+1 issued before the MFMA section.
// ---------------------------------------------------------------------------
#define AROW 40  // padded A LDS row (bf16 elems)
__global__ __launch_bounds__(256) void gemm_kernel(
    const float* __restrict__ adj, const unsigned short* __restrict__ uT,
    const float* __restrict__ dinv, float* __restrict__ part, int KC) {
  __shared__ __align__(16) unsigned char smem[43008];
  unsigned short* Al = (unsigned short*)smem;      // [2][64*AROW] = 10240 B
  unsigned char* Bb = smem + 10240;                // [2][256 * 64 B] = 32768 B
  float* Cs = (float*)smem;                        // epilogue staging (32 KB)

  int tid = threadIdx.x;
  int lane = tid & 63, wave = tid >> 6;
  size_t i0 = (size_t)blockIdx.x * 64;
  int s = blockIdx.y;
  int kbase = s * KC;

  // ---- A staging map: rows lr, lr+32; 16-B piece lo ----
  int lr = tid >> 3, lo = tid & 7;
  const float* gA0 = adj + (i0 + lr) * (size_t)N_NODES + kbase + lo * 4;
  const float* gA1 = gA0 + (size_t)32 * N_NODES;
  const float* gD = dinv + kbase + lo * 4;

  // ---- B DMA map: issue q covers LDS rows q*64+wave*16 .. +15 ----
  // lane -> row r=lane>>2, storage col c=lane&3 holds data octet
  // d = c ^ ((n>>1)&3) = (lane&3) ^ ((lane>>3)&3)  (q,wave drop out mod 4)
  {
  }
  int dOct = (lane & 3) ^ ((lane >> 3) & 3);
  const unsigned short* gB0 =
      uT + (size_t)(wave * 16 + (lane >> 2)) * N_NODES + kbase + dOct * 8;

  f32x4 acc[4][4];
#pragma unroll
  for (int mf = 0; mf < 4; ++mf)
#pragma unroll
    for (int nf = 0; nf < 4; ++nf) acc[mf][nf] = (f32x4){0.f, 0.f, 0.f, 0.f};

  int arow = lane & 15, akq = lane >> 4;
  // B fragment byte offsets (per-thread constants)
  int boff[4];
#pragma unroll
  for (int nf = 0; nf < 4; ++nf) {
    int nb = wave * 64 + nf * 16 + arow;
    int cst = akq ^ ((nb >> 1) & 3);
    boff[nf] = nb * 64 + cst * 16;
  }

  float4 av0, av1, dv;

  auto issueB = [&](int buf, int kk) {
    unsigned char* bb = Bb + buf * 16384 + (wave * 16) * 64;
#pragma unroll
    for (int q = 0; q < 4; ++q)
      async16(gB0 + (size_t)q * 64 * N_NODES + kk, bb + q * 64 * 64);
  };
  auto loadA = [&](int kk) {
    av0 = *(const float4*)(gA0 + kk);
    av1 = *(const float4*)(gA1 + kk);
    dv = *(const float4*)(gD + kk);
  };
  auto storeA = [&](int buf) {
    unsigned short* A = Al + buf * (64 * AROW);
    uint2 w0, w1;
    w0.x = pack2(av0.x * dv.x, av0.y * dv.y);
    w0.y = pack2(av0.z * dv.z, av0.w * dv.w);
    w1.x = pack2(av1.x * dv.x, av1.y * dv.y);
    w1.y = pack2(av1.z * dv.z, av1.w * dv.w);
    *(uint2*)&A[lr * AROW + lo * 4] = w0;
    *(uint2*)&A[(lr + 32) * AROW + lo * 4] = w1;
  };

  issueB(0, 0);
  loadA(0);
  storeA(0);
  __syncthreads();  // vmcnt(0) drain covers the DMAs

  int nIter = KC >> 5;
  for (int it = 0; it < nIter; ++it) {
    int cur = it & 1;
    if (it + 1 < nIter) {
      issueB(cur ^ 1, (it + 1) << 5);  // DMA overlaps MFMA section
      loadA((it + 1) << 5);
    }

    const unsigned short* A = Al + cur * (64 * AROW);
    const unsigned char* B = Bb + cur * 16384;
    bf16x8 a[4], b[4];
#pragma unroll
    for (int mf = 0; mf < 4; ++mf)
      a[mf] = *reinterpret_cast<const bf16x8*>(&A[(mf * 16 + arow) * AROW + akq * 8]);
#pragma unroll
    for (int nf = 0; nf < 4; ++nf)
      b[nf] = *reinterpret_cast<const bf16x8*>(B + boff[nf]);
#pragma unroll
    for (int mf = 0; mf < 4; ++mf)
#pragma unroll
      for (int nf = 0; nf < 4; ++nf)
        acc[mf][nf] = __builtin_amdgcn_mfma_f32_16x16x32_bf16(a[mf], b[nf], acc[mf][nf], 0, 0, 0);

    if (it + 1 < nIter) storeA(cur ^ 1);
    __syncthreads();
  }

  // ---- epilogue: stage C through LDS, store full 1-KB rows ----
  float* pb = part + (size_t)s * ((size_t)N_NODES * DIM);
  int crow = (lane >> 4) * 4;
  int ccol = lane & 15;
#pragma unroll
  for (int p = 0; p < 2; ++p) {
    if (p) __syncthreads();
#pragma unroll
    for (int mf2 = 0; mf2 < 2; ++mf2) {
      int mf = p * 2 + mf2;
#pragma unroll
      for (int nf = 0; nf < 4; ++nf)
#pragma unroll
        for (int r = 0; r < 4; ++r)
          Cs[(mf2 * 16 + crow + r) * 256 + wave * 64 + nf * 16 + ccol] = acc[mf][nf][r];
    }
    __syncthreads();
#pragma unroll
    for (int it = 0; it < 8; ++it) {
      int f = tid + it * 256;
      int row = f >> 6, c4 = f & 63;
      *(float4*)(pb + (i0 + p * 32 + row) * (size_t)DIM + c4 * 4) =
          *(const float4*)(Cs + row * 256 + c4 * 4);
    }
  }
}

// ---------------------------------------------------------------------------
// Kernel 3: out[i,k] = relu(d_i * sum_s part[s][i,k] + d_i^2 * u[i,k])
// ---------------------------------------------------------------------------
__global__ __launch_bounds__(256) void reduce_kernel(
    const float* __restrict__ part, const unsigned short* __restrict__ urm,
    const float* __restrict__ dinv, float* __restrict__ out, int S) {
  size_t idx = ((size_t)blockIdx.x * 256 + threadIdx.x) * 4;
  int i = (int)(idx >> 8);
  const size_t stride = (size_t)N_NODES * DIM;
  float4 v = *(const float4*)(part + idx);
  if (S == 8) {
#pragma unroll
    for (int s = 1; s < 8; ++s) {
      float4 p = *(const float4*)(part + (size_t)s * stride + idx);
      v.x += p.x; v.y += p.y; v.z += p.z; v.w += p.w;
    }
  } else {
    for (int s = 1; s < S; ++s) {
      float4 p = *(const float4*)(part + (size_t)s * stride + idx);
      v.x += p.x; v.y += p.y; v.z += p.z; v.w += p.w;
    }
  }
  ushort4 t = *(const ushort4*)(urm + idx);
  float d = dinv[i];
  float dd = d * d;
  float4 o;
  o.x = fmaxf(0.f, d * v.x + dd * bf2f(t.x));
  o.y = fmaxf(0.f, d * v.y + dd * bf2f(t.y));
  o.z = fmaxf(0.f, d * v.z + dd * bf2f(t.z));
  o.w = fmaxf(0.f, d * v.w + dd * bf2f(t.w));
  *(float4*)(out + idx) = o;
}

// ---------------------------------------------------------------------------
extern "C" void kernel_launch(void* const* d_in, const int* in_sizes, int n_in,
                              void* d_out, int out_size, void* d_ws, size_t ws_size,
                              hipStream_t stream) {
  const float* x = (const float*)d_in[0];
  const float* adj = (const float*)d_in[1];
  const float* W = (const float*)d_in[2];
  float* out = (float*)d_out;
  char* ws = (char*)d_ws;

  // ws layout: dinv (32 KiB) | uT (4 MiB) | urm (4 MiB) | partials (S x 8 MiB)
  float* dinv = (float*)ws;
  unsigned short* uT = (unsigned short*)(ws + 32768);
  unsigned short* urm = (unsigned short*)(ws + 32768 + (size_t)N_NODES * DIM * 2);
  size_t base = 32768 + 2 * (size_t)N_NODES * DIM * 2;
  size_t pbytes = (size_t)N_NODES * DIM * 4;

  int S;
  float* part;
  if (base + 8 * pbytes <= ws_size) { S = 8; part = (float*)(ws + base); }
  else if (base + 4 * pbytes <= ws_size) { S = 4; part = (float*)(ws + base); }
  else if (base + 2 * pbytes <= ws_size) { S = 2; part = (float*)(ws + base); }
  else if (base + 1 * pbytes <= ws_size) { S = 1; part = (float*)(ws + base); }
  else { S = 1; part = out; }  // in-place fallback

  fused_pre_kernel<<<256 + N_NODES, 256, 0, stream>>>(adj, x, W, dinv, uT, urm);
  gemm_kernel<<<dim3(N_NODES / 64, S), 256, 0, stream>>>(adj, uT, dinv, part, N_NODES / S);
  reduce_kernel<<<(N_NODES * DIM) / 1024, 256, 0, stream>>>(part, urm, dinv, out, S);
}